// Round 2
// baseline (381.333 us; speedup 1.0000x reference)
//
#include <hip/hip_runtime.h>
#include <hip/hip_bf16.h>
#include <math.h>

#define N_NODES 100000
#define N_EDGES 1600000
#define IN_F 256
#define HID 32
#define OUTC 16

// ---------------- Kernel 1: h1 = x@W1a^T + b1a ; out1 = h1@W1b^T + b1b ----------------
// 64 nodes per block, 256 threads. LDS: x tile (padded), W1a (padded), h tile, W1b.
__global__ __launch_bounds__(256) void k1_layer1_dense(
    const float* __restrict__ x,
    const float* __restrict__ w1a_w, const float* __restrict__ w1a_b,
    const float* __restrict__ w1b_w, const float* __restrict__ w1b_b,
    float* __restrict__ h1, float* __restrict__ out1)
{
    __shared__ float xs[64][260];   // 66.6 KB, stride 260 -> 2-way bank alias (free), float4-aligned
    __shared__ float ws[32][260];   // 33.3 KB W1a
    __shared__ float hs[64][33];    // 8.4 KB  h1 tile
    __shared__ float wbs[32][33];   // 4.2 KB  W1b

    const int t = threadIdx.x;
    const int node0 = blockIdx.x * 64;
    const int nrem = N_NODES - node0;      // >=1; last block has 32

    // load W1a [32][256]
    for (int i = t; i < 32 * 256; i += 256)
        ws[i >> 8][i & 255] = w1a_w[i];
    // load W1b [32][32]
    for (int i = t; i < 32 * 32; i += 256)
        wbs[i >> 5][i & 31] = w1b_w[i];
    // load x tile [64][256] as float4
    {
        const float4* xg = (const float4*)(x + (size_t)node0 * IN_F);
        for (int i = t; i < 64 * 64; i += 256) {
            int r = i >> 6, c4 = i & 63;
            float4 v = make_float4(0.f, 0.f, 0.f, 0.f);
            if (r < nrem) v = xg[(size_t)r * 64 + c4];
            ((float4*)&xs[r][0])[c4] = v;
        }
    }
    __syncthreads();

    const int o2 = t & 15;     // outputs o2 and o2+16
    const int g  = t >> 4;     // node group 0..15 -> nodes g*4 .. g*4+3

    float acc[4][2] = {};
    const float* wr0 = &ws[o2][0];
    const float* wr1 = &ws[o2 + 16][0];
    #pragma unroll 4
    for (int k = 0; k < 256; k += 4) {
        const float4 w40 = *(const float4*)(wr0 + k);
        const float4 w41 = *(const float4*)(wr1 + k);
        #pragma unroll
        for (int j = 0; j < 4; ++j) {
            const float4 x4 = *(const float4*)&xs[g * 4 + j][k];
            acc[j][0] += x4.x * w40.x + x4.y * w40.y + x4.z * w40.z + x4.w * w40.w;
            acc[j][1] += x4.x * w41.x + x4.y * w41.y + x4.z * w41.z + x4.w * w41.w;
        }
    }

    const float b0 = w1a_b[o2];
    const float b1 = w1a_b[o2 + 16];
    #pragma unroll
    for (int j = 0; j < 4; ++j) {
        const int ln = g * 4 + j;
        const float v0 = acc[j][0] + b0;
        const float v1 = acc[j][1] + b1;
        hs[ln][o2]      = v0;
        hs[ln][o2 + 16] = v1;
        if (ln < nrem) {
            h1[(size_t)(node0 + ln) * HID + o2]      = v0;
            h1[(size_t)(node0 + ln) * HID + o2 + 16] = v1;
        }
    }
    __syncthreads();

    // f_new = h1 @ W1b^T + b1b
    const float bb0 = w1b_b[o2];
    const float bb1 = w1b_b[o2 + 16];
    float f[4][2] = {};
    for (int c = 0; c < 32; ++c) {
        const float wv0 = wbs[o2][c];
        const float wv1 = wbs[o2 + 16][c];
        #pragma unroll
        for (int j = 0; j < 4; ++j) {
            const float hv = hs[g * 4 + j][c];
            f[j][0] += hv * wv0;
            f[j][1] += hv * wv1;
        }
    }
    #pragma unroll
    for (int j = 0; j < 4; ++j) {
        const int ln = g * 4 + j;
        if (ln < nrem) {
            out1[(size_t)(node0 + ln) * HID + o2]      = f[j][0] + bb0;
            out1[(size_t)(node0 + ln) * HID + o2 + 16] = f[j][1] + bb1;
        }
    }
}

// ---------------- Kernel 2: scatter-add layer 1 (32 channels) ----------------
__global__ __launch_bounds__(256) void k2_scatter32(
    const int* __restrict__ ei, const float* __restrict__ h1, float* __restrict__ out1)
{
    const int t = threadIdx.x;
    const int e = blockIdx.x * 8 + (t >> 5);
    const int c = t & 31;
    const int src = ei[e];
    const int dst = ei[N_EDGES + e];
    const float v = h1[(size_t)src * HID + c];
    __hip_atomic_fetch_add(&out1[(size_t)dst * HID + c], v,
                           __ATOMIC_RELAXED, __HIP_MEMORY_SCOPE_AGENT);
}

// ---------------- Kernel 3: layer 2 dense: h2 = relu(out1)@W2a^T + b2a ; out2 = h2@W2b^T + b2b ----
__global__ __launch_bounds__(256) void k3_layer2_dense(
    const float* __restrict__ out1,
    const float* __restrict__ w2a_w, const float* __restrict__ w2a_b,
    const float* __restrict__ w2b_w, const float* __restrict__ w2b_b,
    float* __restrict__ h2, float* __restrict__ out2)
{
    __shared__ float rs[64][33];    // relu'd input tile
    __shared__ float h2s[64][17];
    __shared__ float wa[16][33];    // W2a [16][32]
    __shared__ float wb[16][17];    // W2b [16][16]

    const int t = threadIdx.x;
    const int node0 = blockIdx.x * 64;
    const int nrem = N_NODES - node0;

    for (int i = t; i < 16 * 32; i += 256)   // FIX: 512 elements, 256 threads -> loop
        wa[i >> 5][i & 31] = w2a_w[i];
    if (t < 16 * 16) wb[t >> 4][t & 15] = w2b_w[t];
    for (int i = t; i < 64 * 32; i += 256) {
        int r = i >> 5, c = i & 31;
        float v = 0.f;
        if (r < nrem) v = out1[(size_t)(node0 + r) * HID + c];
        rs[r][c] = fmaxf(v, 0.f);
    }
    __syncthreads();

    const int o = t & 15;
    const int g = t >> 4;    // nodes g*4 .. g*4+3

    const float ba = w2a_b[o];
    float acc[4] = {};
    for (int c = 0; c < 32; ++c) {
        const float w = wa[o][c];
        #pragma unroll
        for (int j = 0; j < 4; ++j) acc[j] += rs[g * 4 + j][c] * w;
    }
    #pragma unroll
    for (int j = 0; j < 4; ++j) {
        const int ln = g * 4 + j;
        const float v = acc[j] + ba;
        h2s[ln][o] = v;
        if (ln < nrem) h2[(size_t)(node0 + ln) * OUTC + o] = v;
    }
    __syncthreads();

    const float bbv = w2b_b[o];
    float f[4] = {};
    for (int c = 0; c < 16; ++c) {
        const float w = wb[o][c];
        #pragma unroll
        for (int j = 0; j < 4; ++j) f[j] += h2s[g * 4 + j][c] * w;
    }
    #pragma unroll
    for (int j = 0; j < 4; ++j) {
        const int ln = g * 4 + j;
        if (ln < nrem) out2[(size_t)(node0 + ln) * OUTC + o] = f[j] + bbv;
    }
}

// ---------------- Kernel 4: scatter-add layer 2 (16 channels) ----------------
__global__ __launch_bounds__(256) void k4_scatter16(
    const int* __restrict__ ei, const float* __restrict__ h2, float* __restrict__ out2)
{
    const int t = threadIdx.x;
    const int e = blockIdx.x * 16 + (t >> 4);
    const int c = t & 15;
    const int src = ei[e];
    const int dst = ei[N_EDGES + e];
    const float v = h2[(size_t)src * OUTC + c];
    __hip_atomic_fetch_add(&out2[(size_t)dst * OUTC + c], v,
                           __ATOMIC_RELAXED, __HIP_MEMORY_SCOPE_AGENT);
}

// ---------------- Kernel 5: in-place log_softmax over 16 channels ----------------
__global__ __launch_bounds__(256) void k5_log_softmax(float* __restrict__ out)
{
    const int n = blockIdx.x * 256 + threadIdx.x;
    if (n >= N_NODES) return;
    float4* p = (float4*)(out + (size_t)n * OUTC);
    float4 a0 = p[0], a1 = p[1], a2 = p[2], a3 = p[3];
    float v[16] = { a0.x, a0.y, a0.z, a0.w, a1.x, a1.y, a1.z, a1.w,
                    a2.x, a2.y, a2.z, a2.w, a3.x, a3.y, a3.z, a3.w };
    float m = v[0];
    #pragma unroll
    for (int i = 1; i < 16; ++i) m = fmaxf(m, v[i]);
    float s = 0.f;
    #pragma unroll
    for (int i = 0; i < 16; ++i) s += expf(v[i] - m);
    const float lse = m + logf(s);
    #pragma unroll
    for (int i = 0; i < 16; ++i) v[i] -= lse;
    p[0] = make_float4(v[0], v[1], v[2], v[3]);
    p[1] = make_float4(v[4], v[5], v[6], v[7]);
    p[2] = make_float4(v[8], v[9], v[10], v[11]);
    p[3] = make_float4(v[12], v[13], v[14], v[15]);
}

extern "C" void kernel_launch(void* const* d_in, const int* in_sizes, int n_in,
                              void* d_out, int out_size, void* d_ws, size_t ws_size,
                              hipStream_t stream)
{
    const float* x      = (const float*)d_in[0];
    const float* w1a_w  = (const float*)d_in[1];
    const float* w1a_b  = (const float*)d_in[2];
    const float* w1b_w  = (const float*)d_in[3];
    const float* w1b_b  = (const float*)d_in[4];
    const float* w2a_w  = (const float*)d_in[5];
    const float* w2a_b  = (const float*)d_in[6];
    const float* w2b_w  = (const float*)d_in[7];
    const float* w2b_b  = (const float*)d_in[8];
    const int*   ei     = (const int*)d_in[9];
    float* out = (float*)d_out;

    float* h1   = (float*)d_ws;                       // N*32 f32 = 12.8 MB
    float* out1 = h1 + (size_t)N_NODES * HID;         // N*32 f32 = 12.8 MB
    float* h2   = out1 + (size_t)N_NODES * HID;       // N*16 f32 = 6.4 MB

    const int nblk = (N_NODES + 63) / 64;             // 1563

    k1_layer1_dense<<<nblk, 256, 0, stream>>>(x, w1a_w, w1a_b, w1b_w, w1b_b, h1, out1);
    k2_scatter32<<<N_EDGES / 8, 256, 0, stream>>>(ei, h1, out1);
    k3_layer2_dense<<<nblk, 256, 0, stream>>>(out1, w2a_w, w2a_b, w2b_w, w2b_b, h2, out);
    k4_scatter16<<<N_EDGES / 16, 256, 0, stream>>>(ei, h2, out);
    k5_log_softmax<<<(N_NODES + 255) / 256, 256, 0, stream>>>(out);
}